// Round 5
// baseline (12.271 us; speedup 1.0000x reference)
//
#include <hip/hip_runtime.h>
#include <math.h>
#include <stdint.h>

// Problem shape (fixed by setup_inputs): B=512, M=256, K=2.
// Only the diagonal of the (B,B) kernel matrix survives:
//   out = (1/(B*K*M)) * sum_{i,k,m} exp(-0.5*d^2) * inv_std[i,m] / sqrt(2pi)
//   d = (z2[k*B+i,m] - z1[i,m]) * inv_std[i,m],  inv_std = exp(-0.5*z1[i,M+m])
#define PB 512
#define PM 256

#define GRID1 128               // blocks; 4 waves/block, one wave per sample row
#define ROWS_PER_BLK 4
#define SLOT_STRIDE 16          // u64s: 128 B -> one cache line per slot

// inv_sqrt(2*pi) / (B*K*M)
#define SCALE (0.3989422804014327f / (512.0f * 512.0f))

// Ready tag lives in the HIGH 32 bits of the packed slot; low 32 bits are the
// fp32 partial's bit pattern. Slots are reset to 0 at the end of every call,
// so replays always enter with slots==0. First-ever call sees 0xAAAAAAAA
// poison (high word != MAGIC) or zeroed pages -- both read as "not ready".
#define MAGIC 0x5EEDBEEFu

// Single kernel, single graph node. 127 producer blocks + 1 consumer block.
// Each producer packs (MAGIC | partial) into its own cache-line-padded u64
// slot with a device-scope release store: one atomic load on the consumer
// side gets readiness AND the value, and no two producers share a line, so
// there is no cross-XCD line ping-pong on the handoff.
__global__ __launch_bounds__(256)
void pp_onenode(const float* __restrict__ z1,
                const float* __restrict__ z2,
                uint64_t* __restrict__ slots,
                float* __restrict__ out) {
    const int wave = threadIdx.x >> 6;     // 0..3, one sample row per wave
    const int lane = threadIdx.x & 63;     // 64 lanes x float4 = 256 features
    const int i = blockIdx.x * ROWS_PER_BLK + wave;

    // Vectorized row loads: 16 B/lane, fully coalesced.
    const float4 mean = ((const float4*)&z1[i * (2 * PM)])[lane];
    const float4 lv   = ((const float4*)&z1[i * (2 * PM) + PM])[lane];
    const float4 x0   = ((const float4*)&z2[i * PM])[lane];               // k=0
    const float4 x1   = ((const float4*)&z2[(PB + i) * PM])[lane];        // k=1

    float acc = 0.0f;
    {
        const float is = __expf(-0.5f * lv.x);
        const float d0 = (x0.x - mean.x) * is, d1 = (x1.x - mean.x) * is;
        acc += (__expf(-0.5f * d0 * d0) + __expf(-0.5f * d1 * d1)) * is;
    }
    {
        const float is = __expf(-0.5f * lv.y);
        const float d0 = (x0.y - mean.y) * is, d1 = (x1.y - mean.y) * is;
        acc += (__expf(-0.5f * d0 * d0) + __expf(-0.5f * d1 * d1)) * is;
    }
    {
        const float is = __expf(-0.5f * lv.z);
        const float d0 = (x0.z - mean.z) * is, d1 = (x1.z - mean.z) * is;
        acc += (__expf(-0.5f * d0 * d0) + __expf(-0.5f * d1 * d1)) * is;
    }
    {
        const float is = __expf(-0.5f * lv.w);
        const float d0 = (x0.w - mean.w) * is, d1 = (x1.w - mean.w) * is;
        acc += (__expf(-0.5f * d0 * d0) + __expf(-0.5f * d1 * d1)) * is;
    }

    // Wave (64-lane) reduction
    #pragma unroll
    for (int off = 32; off > 0; off >>= 1)
        acc += __shfl_down(acc, off, 64);

    // Cross-wave reduction (4 waves) -> one partial per block
    __shared__ float partial[4];
    if (lane == 0) partial[wave] = acc;
    __syncthreads();
    if (threadIdx.x == 0) {
        const float p = partial[0] + partial[1] + partial[2] + partial[3];
        uint32_t bits = __float_as_uint(p);
        uint64_t packed = ((uint64_t)MAGIC << 32) | (uint64_t)bits;
        __hip_atomic_store(&slots[blockIdx.x * SLOT_STRIDE], packed,
                           __ATOMIC_RELEASE, __HIP_MEMORY_SCOPE_AGENT);
    }

    // Consumer: block 0, first wave. Lane l owns slots l and l+64.
    if (blockIdx.x == 0 && threadIdx.x < 64) {
        const int l = threadIdx.x;
        uint64_t a, b;
        do {
            a = __hip_atomic_load(&slots[l * SLOT_STRIDE],
                                  __ATOMIC_ACQUIRE, __HIP_MEMORY_SCOPE_AGENT);
        } while ((uint32_t)(a >> 32) != MAGIC);
        do {
            b = __hip_atomic_load(&slots[(l + 64) * SLOT_STRIDE],
                                  __ATOMIC_ACQUIRE, __HIP_MEMORY_SCOPE_AGENT);
        } while ((uint32_t)(b >> 32) != MAGIC);

        float v = __uint_as_float((uint32_t)a) + __uint_as_float((uint32_t)b);
        #pragma unroll
        for (int off = 32; off > 0; off >>= 1)
            v += __shfl_down(v, off, 64);
        if (l == 0) out[0] = v * SCALE;

        // Reset slots to 0 so the next replay starts "not ready".
        __hip_atomic_store(&slots[l * SLOT_STRIDE], (uint64_t)0,
                           __ATOMIC_RELAXED, __HIP_MEMORY_SCOPE_AGENT);
        __hip_atomic_store(&slots[(l + 64) * SLOT_STRIDE], (uint64_t)0,
                           __ATOMIC_RELAXED, __HIP_MEMORY_SCOPE_AGENT);
    }
}

extern "C" void kernel_launch(void* const* d_in, const int* in_sizes, int n_in,
                              void* d_out, int out_size, void* d_ws, size_t ws_size,
                              hipStream_t stream) {
    const float* z1 = (const float*)d_in[0];  // (512, 512) fp32
    const float* z2 = (const float*)d_in[1];  // (1024, 256) fp32
    float* out = (float*)d_out;               // 1 fp32 scalar
    uint64_t* slots = (uint64_t*)d_ws;        // 128 line-padded u64 slots (16 KiB)

    pp_onenode<<<GRID1, 256, 0, stream>>>(z1, z2, slots, out);
}

// Round 6
// 10.023 us; speedup vs baseline: 1.2244x; 1.2244x over previous
//
#include <hip/hip_runtime.h>
#include <math.h>

// Problem shape (fixed by setup_inputs): B=512, M=256, K=2.
// Only the diagonal of the (B,B) kernel matrix survives:
//   out = (1/(B*K*M)) * sum_{i,k,m} exp(-0.5*d^2) * inv_std[i,m] / sqrt(2pi)
//   d = (z2[k*B+i,m] - z1[i,m]) * inv_std[i,m],  inv_std = exp(-0.5*z1[i,M+m])
#define PB 512
#define PM 256

#define GRID1 128               // blocks; 4 waves/block, one wave per sample row
#define ROWS_PER_BLK 4

// inv_sqrt(2*pi) / (B*K*M)
#define SCALE (0.3989422804014327f / (512.0f * 512.0f))

// "partial ready" tag. Flags are reset to 0 at the end of every call, so
// replays always enter with flags==0. First-ever call sees 0xAAAAAAAA poison
// or zeroed pages -- both != MAGIC.
#define MAGIC 0x5EEDBEEFu

// Single kernel, single graph node. 127 producer blocks + 1 block that also
// consumes: block 0's first wave spins on per-block ready flags (device-scope
// acquire, safe across non-coherent XCD L2s), reduces the 128 partials,
// writes the scalar, and resets the flags for the next replay.
// Flags + partials are COMPACT (~10 cache lines total): the consumer wave is
// the critical path and every extra line it touches is a cold cross-XCD miss
// (the padded-slot variant touched 128 lines and regressed 10.1 -> 12.3 us).
// No grid-wide barrier: only 1 block waits, and the 127 others dispatch
// freely on the remaining CUs, so there is no circular wait.
__global__ __launch_bounds__(256)
void pp_onenode(const float* __restrict__ z1,
                const float* __restrict__ z2,
                float* __restrict__ ws,
                float* __restrict__ out) {
    float*    partials = ws;                              // 128 floats
    uint32_t* flags    = (uint32_t*)(ws + 256);           // 128 u32, +1 KiB

    const int wave = threadIdx.x >> 6;     // 0..3, one sample row per wave
    const int lane = threadIdx.x & 63;     // 64 lanes x float4 = 256 features
    const int i = blockIdx.x * ROWS_PER_BLK + wave;

    // Vectorized row loads: 16 B/lane, fully coalesced.
    const float4 mean = ((const float4*)&z1[i * (2 * PM)])[lane];
    const float4 lv   = ((const float4*)&z1[i * (2 * PM) + PM])[lane];
    const float4 x0   = ((const float4*)&z2[i * PM])[lane];               // k=0
    const float4 x1   = ((const float4*)&z2[(PB + i) * PM])[lane];        // k=1

    float acc = 0.0f;
    {
        const float is = __expf(-0.5f * lv.x);
        const float d0 = (x0.x - mean.x) * is, d1 = (x1.x - mean.x) * is;
        acc += (__expf(-0.5f * d0 * d0) + __expf(-0.5f * d1 * d1)) * is;
    }
    {
        const float is = __expf(-0.5f * lv.y);
        const float d0 = (x0.y - mean.y) * is, d1 = (x1.y - mean.y) * is;
        acc += (__expf(-0.5f * d0 * d0) + __expf(-0.5f * d1 * d1)) * is;
    }
    {
        const float is = __expf(-0.5f * lv.z);
        const float d0 = (x0.z - mean.z) * is, d1 = (x1.z - mean.z) * is;
        acc += (__expf(-0.5f * d0 * d0) + __expf(-0.5f * d1 * d1)) * is;
    }
    {
        const float is = __expf(-0.5f * lv.w);
        const float d0 = (x0.w - mean.w) * is, d1 = (x1.w - mean.w) * is;
        acc += (__expf(-0.5f * d0 * d0) + __expf(-0.5f * d1 * d1)) * is;
    }

    // Wave (64-lane) reduction
    #pragma unroll
    for (int off = 32; off > 0; off >>= 1)
        acc += __shfl_down(acc, off, 64);

    // Cross-wave reduction (4 waves) -> one partial per block
    __shared__ float partial[4];
    if (lane == 0) partial[wave] = acc;
    __syncthreads();
    if (threadIdx.x == 0) {
        const float p = partial[0] + partial[1] + partial[2] + partial[3];
        partials[blockIdx.x] = p;
        // Release-publish: partial store above becomes visible before MAGIC.
        __hip_atomic_store(&flags[blockIdx.x], MAGIC,
                           __ATOMIC_RELEASE, __HIP_MEMORY_SCOPE_AGENT);
    }

    // Consumer: block 0, first wave. Lane l owns flags l and l+64.
    if (blockIdx.x == 0 && threadIdx.x < 64) {
        const int l = threadIdx.x;
        while (__hip_atomic_load(&flags[l], __ATOMIC_ACQUIRE,
                                 __HIP_MEMORY_SCOPE_AGENT) != MAGIC) {}
        while (__hip_atomic_load(&flags[l + 64], __ATOMIC_ACQUIRE,
                                 __HIP_MEMORY_SCOPE_AGENT) != MAGIC) {}
        // Device-scope loads of the partials (bypass potentially stale L1).
        float v = __hip_atomic_load(&partials[l], __ATOMIC_RELAXED,
                                    __HIP_MEMORY_SCOPE_AGENT)
                + __hip_atomic_load(&partials[l + 64], __ATOMIC_RELAXED,
                                    __HIP_MEMORY_SCOPE_AGENT);
        #pragma unroll
        for (int off = 32; off > 0; off >>= 1)
            v += __shfl_down(v, off, 64);
        if (l == 0) out[0] = v * SCALE;

        // Reset flags so the next replay starts from 0 (deterministic;
        // end-of-kernel release makes these visible to the next launch).
        flags[l] = 0;
        flags[l + 64] = 0;
    }
}

extern "C" void kernel_launch(void* const* d_in, const int* in_sizes, int n_in,
                              void* d_out, int out_size, void* d_ws, size_t ws_size,
                              hipStream_t stream) {
    const float* z1 = (const float*)d_in[0];  // (512, 512) fp32
    const float* z2 = (const float*)d_in[1];  // (1024, 256) fp32
    float* out = (float*)d_out;               // 1 fp32 scalar
    float* ws  = (float*)d_ws;                // partials + flags scratch

    pp_onenode<<<GRID1, 256, 0, stream>>>(z1, z2, ws, out);
}